// Round 4
// baseline (229.204 us; speedup 1.0000x reference)
//
#include <hip/hip_runtime.h>

typedef unsigned short u16;
typedef __bf16 bf16x8 __attribute__((ext_vector_type(8)));
typedef __bf16 bf16x4 __attribute__((ext_vector_type(4)));
typedef __bf16 bf16x2 __attribute__((ext_vector_type(2)));
typedef short s16x4 __attribute__((ext_vector_type(4)));
typedef float f32x4 __attribute__((ext_vector_type(4)));

#define Mdim 4096
#define Ndim 1024
#define Kdim 1024

__device__ __forceinline__ u16 f2bf(float f) {
    unsigned u = __float_as_uint(f);
    u += 0x7FFF + ((u >> 16) & 1);   // RNE
    return (u16)(u >> 16);
}

// async global->LDS, 16B/lane; LDS dst = wave-uniform base + lane*16
__device__ __forceinline__ void gl_lds16(const u16* g, u16* l) {
    __builtin_amdgcn_global_load_lds(
        (const __attribute__((address_space(1))) unsigned int*)g,
        (__attribute__((address_space(3))) unsigned int*)l, 16, 0, 0);
}

__device__ __forceinline__ f32x4 mfma16(s16x4 a, s16x4 b, f32x4 c) {
#if __has_builtin(__builtin_amdgcn_mfma_f32_16x16x16_bf16)
    return __builtin_amdgcn_mfma_f32_16x16x16_bf16(
        __builtin_bit_cast(bf16x4, a), __builtin_bit_cast(bf16x4, b), c, 0, 0, 0);
#else
    return __builtin_amdgcn_mfma_f32_16x16x16bf16_1k(a, b, c, 0, 0, 0);
#endif
}

#if __has_builtin(__builtin_amdgcn_exp2f)
#define EXP2(x) __builtin_amdgcn_exp2f(x)
#else
#define EXP2(x) exp2f(x)
#endif

__device__ __forceinline__ s16x4 pack4bf(float a, float b, float c, float d) {
#if __has_builtin(__builtin_amdgcn_cvt_pk_bf16_f32)
    union { struct { bf16x2 lo, hi; } v; s16x4 s; } u;
    u.v.lo = __builtin_amdgcn_cvt_pk_bf16_f32(a, b);
    u.v.hi = __builtin_amdgcn_cvt_pk_bf16_f32(c, d);
    return u.s;
#else
    s16x4 r;
    r.x = (short)f2bf(a); r.y = (short)f2bf(b);
    r.z = (short)f2bf(c); r.w = (short)f2bf(d);
    return r;
#endif
}

// ---------------------------------------------------------------------------
// Kernel 1: cast X and Wq/Wk/Wv/Wo fp32 -> bf16
// ---------------------------------------------------------------------------
__global__ __launch_bounds__(256) void cast_all(
    const float* __restrict__ X,
    const float* __restrict__ Wq, const float* __restrict__ Wk,
    const float* __restrict__ Wv, const float* __restrict__ Wo,
    u16* __restrict__ Xb,
    u16* __restrict__ Wqb, u16* __restrict__ Wkb,
    u16* __restrict__ Wvb, u16* __restrict__ Wob) {
    size_t i4 = (size_t)blockIdx.x * blockDim.x + threadIdx.x;
    size_t flat = i4 * 4;
    const float* src;
    u16* dst;
    size_t off;
    if (flat < (size_t)4194304) {
        src = X; dst = Xb; off = flat;
    } else {
        size_t r = flat - 4194304;
        int w = (int)(r >> 20);
        off = r & 1048575;
        src = (w == 0) ? Wq : (w == 1) ? Wk : (w == 2) ? Wv : Wo;
        dst = (w == 0) ? Wqb : (w == 1) ? Wkb : (w == 2) ? Wvb : Wob;
    }
    float4 v = *(const float4*)(src + off);
    ushort4 o;
    o.x = f2bf(v.x); o.y = f2bf(v.y); o.z = f2bf(v.z); o.w = f2bf(v.w);
    *(ushort4*)(dst + off) = o;
}

// ---------------------------------------------------------------------------
// GEMM core (m97-style, XOR-swizzled global_load_lds staging).
// ---------------------------------------------------------------------------
template <int BN>
__device__ __forceinline__ void gemm_core(const u16* __restrict__ A,
                                          const u16* __restrict__ Bw,
                                          const float* __restrict__ bias,
                                          void* __restrict__ out,
                                          int n0, int mode) {
    __shared__ __align__(16) u16 At[128 * 64];
    __shared__ __align__(16) u16 Bt[BN * 64];
    const int tid = threadIdx.x, w = tid >> 6, lane = tid & 63;
    const int quad = lane >> 4, l16 = lane & 15;
    const int wm = w & 1, wn = w >> 1;
    const int m0 = blockIdx.x * 128;
    constexpr int NTN = BN / 32;
    f32x4 acc[4][NTN] = {};
    const int r8 = lane >> 3, c8 = lane & 7;

    for (int k0 = 0; k0 < Kdim; k0 += 64) {
        __syncthreads();
#pragma unroll
        for (int i = 0; i < 4; ++i) {
            int row = w * 32 + i * 8 + r8;
            int j = c8 ^ (row & 7);
            gl_lds16(A + (size_t)(m0 + row) * Kdim + k0 + j * 8,
                     &At[(w * 32 + i * 8) * 64]);
        }
#pragma unroll
        for (int i = 0; i < BN / 32; ++i) {
            int row = w * (BN / 4) + i * 8 + r8;
            int j = c8 ^ (row & 7);
            gl_lds16(Bw + (size_t)(n0 + row) * Kdim + k0 + j * 8,
                     &Bt[(w * (BN / 4) + i * 8) * 64]);
        }
        __syncthreads();
#pragma unroll
        for (int ks = 0; ks < 2; ++ks) {
            bf16x8 af[4], bf[NTN];
#pragma unroll
            for (int mt = 0; mt < 4; ++mt) {
                int r = wm * 64 + mt * 16 + l16;
                af[mt] = *(const bf16x8*)&At[r * 64 + ((ks * 4 + quad) ^ (r & 7)) * 8];
            }
#pragma unroll
            for (int nt = 0; nt < NTN; ++nt) {
                int r = wn * (BN / 2) + nt * 16 + l16;
                bf[nt] = *(const bf16x8*)&Bt[r * 64 + ((ks * 4 + quad) ^ (r & 7)) * 8];
            }
#pragma unroll
            for (int mt = 0; mt < 4; ++mt)
#pragma unroll
                for (int nt = 0; nt < NTN; ++nt)
                    acc[mt][nt] = __builtin_amdgcn_mfma_f32_16x16x32_bf16(
                        af[mt], bf[nt], acc[mt][nt], 0, 0, 0);
        }
    }

#pragma unroll
    for (int nt = 0; nt < NTN; ++nt) {
        int n = n0 + wn * (BN / 2) + nt * 16 + l16;
        float bb = bias[n];
#pragma unroll
        for (int mt = 0; mt < 4; ++mt) {
            int mbase = m0 + wm * 64 + mt * 16 + quad * 4;
            if (mode == 2) {
                int b = mbase >> 11, t = mbase & 2047;
                int h = n >> 6, d = n & 63;
                ushort4 pk;
                pk.x = f2bf(acc[mt][nt][0] + bb);
                pk.y = f2bf(acc[mt][nt][1] + bb);
                pk.z = f2bf(acc[mt][nt][2] + bb);
                pk.w = f2bf(acc[mt][nt][3] + bb);
                *(ushort4*)&((u16*)out)[(((size_t)(b * 16 + h) * 64 + d) << 11) + t] = pk;
            } else if (mode == 0) {
#pragma unroll
                for (int r = 0; r < 4; ++r) {
                    int m = mbase + r;
                    int b = m >> 11, t = m & 2047, h = n >> 6, d = n & 63;
                    ((u16*)out)[(((size_t)(b * 16 + h) * 2048 + t) << 6) + d] =
                        f2bf(acc[mt][nt][r] + bb);
                }
            } else {
#pragma unroll
                for (int r = 0; r < 4; ++r)
                    ((float*)out)[(size_t)(mbase + r) * Ndim + n] = acc[mt][nt][r] + bb;
            }
        }
    }
}

// fused QKV: grid (32, 24); y<8 -> Q, y<16 -> K, else -> V^T
__global__ __launch_bounds__(256, 2) void qkv_gemm(
    const u16* __restrict__ Xb,
    const u16* __restrict__ Wqb, const u16* __restrict__ Wkb, const u16* __restrict__ Wvb,
    const float* __restrict__ bq, const float* __restrict__ bk, const float* __restrict__ bv,
    u16* __restrict__ Qw, u16* __restrict__ Kw, u16* __restrict__ VTw) {
    const int y = blockIdx.y;
    const int z = y >> 3;
    const int n0 = (y & 7) * 128;
    const u16* Bw = (z == 0) ? Wqb : (z == 1) ? Wkb : Wvb;
    const float* bias = (z == 0) ? bq : (z == 1) ? bk : bv;
    void* out = (z == 0) ? (void*)Qw : (z == 1) ? (void*)Kw : (void*)VTw;
    gemm_core<128>(Xb, Bw, bias, out, n0, (z == 2) ? 2 : 0);
}

__global__ __launch_bounds__(256, 2) void out_gemm(
    const u16* __restrict__ Aatt, const u16* __restrict__ Wob,
    const float* __restrict__ bo, float* __restrict__ out) {
    gemm_core<64>(Aatt, Wob, bo, out, blockIdx.y * 64, 1);
}

// ---------------------------------------------------------------------------
// Flash attention v4: transposed-S, kk-split across the block's 4 waves,
// K/V streamed DIRECTLY into registers (no LDS in the loop, no barriers in
// the loop), register ping-pong prefetch.  Partial O / l combined once in
// LDS at the end (valid because softmax here has no running max).
// Block = 32 q rows; grid = 64 strips x 32 bh = 2048 blocks, heavy first.
// ---------------------------------------------------------------------------
__global__ __launch_bounds__(256, 3) void flash_attn(
    const u16* __restrict__ Q, const u16* __restrict__ K,
    const u16* __restrict__ VT, u16* __restrict__ Aatt) {
    __shared__ __align__(16) float oLds[4 * 2048];   // [wave][32 q][64 d]
    __shared__ float lsumLds[4][32];

    const int tid = threadIdx.x, w = tid >> 6, lane = tid & 63;
    const int quad = lane >> 4, l16 = lane & 15;
    const int g = blockIdx.x;
    const int bh = g & 31;
    const int j = 63 - (g >> 5);          // strip index, heavy (j=63) first
    const int qbase = j * 32;
    const int ntw = j + 1;                // kk tiles for this strip

    const u16* Qh  = Q  + (size_t)bh * 131072;
    const u16* Kh  = K  + (size_t)bh * 131072;
    const u16* VTh = VT + (size_t)bh * 131072;

    // Q fragments (B operand), held for the whole loop
    bf16x8 qf[2][2];
#pragma unroll
    for (int qt = 0; qt < 2; ++qt)
#pragma unroll
        for (int ks = 0; ks < 2; ++ks)
            qf[qt][ks] = *(const bf16x8*)(Qh + (size_t)(qbase + qt * 16 + l16) * 64
                                             + ks * 32 + quad * 8);

    f32x4 o[2][4] = {};
    float lsum[2] = {0.f, 0.f};
    const float c1 = 0.18033688011112042f;   // log2(e)/8

    // fragment loads straight from global:
    //  K (A-op of S^T): ka[c][ks] = K[kk0+c*16+l16][ks*32+quad*8 ..+7]  (16B)
    //  V (B-op of PV):  vf[c][dt] = VT[dt*16+l16][kk0+c*16+quad*4 ..+3] (8B)
#define LOAD_TILE(kt_, ka_, vf_)                                               \
    {                                                                          \
        const u16* kp_ = Kh + (size_t)(kt_) * 2048;                            \
        const u16* vp_ = VTh + (kt_) * 32;                                     \
        _Pragma("unroll")                                                      \
        for (int c_ = 0; c_ < 2; ++c_) {                                       \
            _Pragma("unroll")                                                  \
            for (int ks_ = 0; ks_ < 2; ++ks_)                                  \
                ka_[c_][ks_] = *(const bf16x8*)(kp_ + (c_ * 16 + l16) * 64     \
                                                + ks_ * 32 + quad * 8);        \
            _Pragma("unroll")                                                  \
            for (int dt_ = 0; dt_ < 4; ++dt_)                                  \
                vf_[c_][dt_] = *(const s16x4*)(vp_ + (size_t)(dt_ * 16 + l16) * 2048 \
                                               + c_ * 16 + quad * 4);          \
        }                                                                      \
    }

#define COMPUTE_TILE(kt_, ka_, vf_)                                            \
    {                                                                          \
        const bool dm_ = ((kt_) == ntw - 1);                                   \
        _Pragma("unroll")                                                      \
        for (int c_ = 0; c_ < 2; ++c_) {                                       \
            _Pragma("unroll")                                                  \
            for (int qt_ = 0; qt_ < 2; ++qt_) {                                \
                f32x4 z_ = {};                                                 \
                z_ = __builtin_amdgcn_mfma_f32_16x16x32_bf16(                  \
                    ka_[c_][0], qf[qt_][0], z_, 0, 0, 0);                      \
                z_ = __builtin_amdgcn_mfma_f32_16x16x32_bf16(                  \
                    ka_[c_][1], qf[qt_][1], z_, 0, 0, 0);                      \
                float p_[4];                                                   \
                if (dm_) {                                                     \
                    int q_ = qbase + qt_ * 16 + l16;                           \
                    int kkb_ = (kt_) * 32 + c_ * 16 + quad * 4;                \
                    _Pragma("unroll")                                          \
                    for (int r_ = 0; r_ < 4; ++r_)                             \
                        p_[r_] = (kkb_ + r_ > q_) ? 0.f : EXP2(z_[r_] * c1);   \
                } else {                                                       \
                    _Pragma("unroll")                                          \
                    for (int r_ = 0; r_ < 4; ++r_) p_[r_] = EXP2(z_[r_] * c1); \
                }                                                              \
                lsum[qt_] += (p_[0] + p_[1]) + (p_[2] + p_[3]);                \
                s16x4 pa_ = pack4bf(p_[0], p_[1], p_[2], p_[3]);               \
                _Pragma("unroll")                                              \
                for (int dt_ = 0; dt_ < 4; ++dt_)                              \
                    o[qt_][dt_] = mfma16(pa_, vf_[c_][dt_], o[qt_][dt_]);      \
            }                                                                  \
        }                                                                      \
    }

    bf16x8 kaA[2][2], kaB[2][2];
    s16x4 vfA[2][4], vfB[2][4];
    int kt = w;                      // round-robin kk-split across waves
    if (kt < ntw) {
        LOAD_TILE(kt, kaA, vfA);
        while (true) {
            int nx = kt + 4;
            if (nx < ntw) LOAD_TILE(nx, kaB, vfB);
            COMPUTE_TILE(kt, kaA, vfA);
            kt = nx;
            if (kt >= ntw) break;
            nx = kt + 4;
            if (nx < ntw) LOAD_TILE(nx, kaA, vfA);
            COMPUTE_TILE(kt, kaB, vfB);
            kt = nx;
            if (kt >= ntw) break;
        }
    }

    // ---- combine the 4 waves' partials (no running max => plain sums) ----
    // o[qt][dt][r]: q = qt*16+quad*4+r, d = dt*16+l16
#pragma unroll
    for (int qt = 0; qt < 2; ++qt) {
        float l = lsum[qt];
        l += __shfl_xor(l, 16);
        l += __shfl_xor(l, 32);
        if (lane < 16) lsumLds[w][qt * 16 + lane] = l;
#pragma unroll
        for (int dt = 0; dt < 4; ++dt)
#pragma unroll
            for (int r = 0; r < 4; ++r)
                oLds[w * 2048 + (qt * 16 + quad * 4 + r) * 64 + dt * 16 + l16] =
                    o[qt][dt][r];
    }
    __syncthreads();

    // thread tid -> q = tid>>3, d = (tid&7)*8 : 8 consecutive d
    {
        const int q = tid >> 3, d = (tid & 7) * 8;
        float l = lsumLds[0][q] + lsumLds[1][q] + lsumLds[2][q] + lsumLds[3][q];
        float inv = 1.0f / l;
        f32x4 a0 = {}, a1 = {};
#pragma unroll
        for (int ww = 0; ww < 4; ++ww) {
            a0 += *(const f32x4*)&oLds[ww * 2048 + q * 64 + d];
            a1 += *(const f32x4*)&oLds[ww * 2048 + q * 64 + d + 4];
        }
        const int b = bh >> 4, h = bh & 15;
        const int t = qbase + q;
        ushort4 p0, p1;
        p0.x = f2bf(a0[0] * inv); p0.y = f2bf(a0[1] * inv);
        p0.z = f2bf(a0[2] * inv); p0.w = f2bf(a0[3] * inv);
        p1.x = f2bf(a1[0] * inv); p1.y = f2bf(a1[1] * inv);
        p1.z = f2bf(a1[2] * inv); p1.w = f2bf(a1[3] * inv);
        u16* dst = Aatt + ((size_t)(b * 2048 + t)) * 1024 + h * 64 + d;
        *(ushort4*)dst = p0;
        *(ushort4*)(dst + 4) = p1;
    }
}

// ---------------------------------------------------------------------------
extern "C" void kernel_launch(void* const* d_in, const int* in_sizes, int n_in,
                              void* d_out, int out_size, void* d_ws, size_t ws_size,
                              hipStream_t stream) {
    const float* X  = (const float*)d_in[0];
    const float* Wq = (const float*)d_in[1];
    const float* bq = (const float*)d_in[2];
    const float* Wk = (const float*)d_in[3];
    const float* bk = (const float*)d_in[4];
    const float* Wv = (const float*)d_in[5];
    const float* bv = (const float*)d_in[6];
    const float* Wo = (const float*)d_in[7];
    const float* bo = (const float*)d_in[8];

    char* ws = (char*)d_ws;
    const size_t MB = 1 << 20;
    u16* Xb   = (u16*)(ws);
    u16* Wqb  = (u16*)(ws + 8  * MB);
    u16* Wkb  = (u16*)(ws + 10 * MB);
    u16* Wvb  = (u16*)(ws + 12 * MB);
    u16* Wob  = (u16*)(ws + 14 * MB);
    u16* Qw   = (u16*)(ws + 16 * MB);   // [bh][t][d]
    u16* Kw   = (u16*)(ws + 24 * MB);   // [bh][t][d]
    u16* VTw  = (u16*)(ws + 32 * MB);   // [bh][d][t]
    u16* Aatt = (u16*)(ws + 40 * MB);   // [B][T][E]

    cast_all<<<8192, 256, 0, stream>>>(X, Wq, Wk, Wv, Wo, Xb, Wqb, Wkb, Wvb, Wob);
    qkv_gemm<<<dim3(32, 24), 256, 0, stream>>>(Xb, Wqb, Wkb, Wvb, bq, bk, bv, Qw, Kw, VTw);
    flash_attn<<<dim3(2048), 256, 0, stream>>>(Qw, Kw, VTw, Aatt);
    out_gemm<<<dim3(32, 16), 256, 0, stream>>>(Aatt, Wob, bo, (float*)d_out);
}

// Round 5
// 192.317 us; speedup vs baseline: 1.1918x; 1.1918x over previous
//
#include <hip/hip_runtime.h>

typedef unsigned short u16;
typedef __bf16 bf16x8 __attribute__((ext_vector_type(8)));
typedef __bf16 bf16x4 __attribute__((ext_vector_type(4)));
typedef __bf16 bf16x2 __attribute__((ext_vector_type(2)));
typedef short s16x4 __attribute__((ext_vector_type(4)));
typedef float f32x4 __attribute__((ext_vector_type(4)));

#define Mdim 4096
#define Ndim 1024
#define Kdim 1024

__device__ __forceinline__ u16 f2bf(float f) {
    unsigned u = __float_as_uint(f);
    u += 0x7FFF + ((u >> 16) & 1);   // RNE
    return (u16)(u >> 16);
}

// async global->LDS, 16B/lane; LDS dst = wave-uniform base + lane*16
__device__ __forceinline__ void gl_lds16(const u16* g, u16* l) {
    __builtin_amdgcn_global_load_lds(
        (const __attribute__((address_space(1))) unsigned int*)g,
        (__attribute__((address_space(3))) unsigned int*)l, 16, 0, 0);
}

__device__ __forceinline__ f32x4 mfma16(s16x4 a, s16x4 b, f32x4 c) {
#if __has_builtin(__builtin_amdgcn_mfma_f32_16x16x16_bf16)
    return __builtin_amdgcn_mfma_f32_16x16x16_bf16(
        __builtin_bit_cast(bf16x4, a), __builtin_bit_cast(bf16x4, b), c, 0, 0, 0);
#else
    return __builtin_amdgcn_mfma_f32_16x16x16bf16_1k(a, b, c, 0, 0, 0);
#endif
}

#if __has_builtin(__builtin_amdgcn_exp2f)
#define EXP2(x) __builtin_amdgcn_exp2f(x)
#else
#define EXP2(x) exp2f(x)
#endif

__device__ __forceinline__ s16x4 pack4bf(float a, float b, float c, float d) {
#if __has_builtin(__builtin_amdgcn_cvt_pk_bf16_f32)
    union { struct { bf16x2 lo, hi; } v; s16x4 s; } u;
    u.v.lo = __builtin_amdgcn_cvt_pk_bf16_f32(a, b);
    u.v.hi = __builtin_amdgcn_cvt_pk_bf16_f32(c, d);
    return u.s;
#else
    s16x4 r;
    r.x = (short)f2bf(a); r.y = (short)f2bf(b);
    r.z = (short)f2bf(c); r.w = (short)f2bf(d);
    return r;
#endif
}

// ---------------------------------------------------------------------------
// Kernel 1: cast X and Wq/Wk/Wv/Wo fp32 -> bf16
// ---------------------------------------------------------------------------
__global__ __launch_bounds__(256) void cast_all(
    const float* __restrict__ X,
    const float* __restrict__ Wq, const float* __restrict__ Wk,
    const float* __restrict__ Wv, const float* __restrict__ Wo,
    u16* __restrict__ Xb,
    u16* __restrict__ Wqb, u16* __restrict__ Wkb,
    u16* __restrict__ Wvb, u16* __restrict__ Wob) {
    size_t i4 = (size_t)blockIdx.x * blockDim.x + threadIdx.x;
    size_t flat = i4 * 4;
    const float* src;
    u16* dst;
    size_t off;
    if (flat < (size_t)4194304) {
        src = X; dst = Xb; off = flat;
    } else {
        size_t r = flat - 4194304;
        int w = (int)(r >> 20);
        off = r & 1048575;
        src = (w == 0) ? Wq : (w == 1) ? Wk : (w == 2) ? Wv : Wo;
        dst = (w == 0) ? Wqb : (w == 1) ? Wkb : (w == 2) ? Wvb : Wob;
    }
    float4 v = *(const float4*)(src + off);
    ushort4 o;
    o.x = f2bf(v.x); o.y = f2bf(v.y); o.z = f2bf(v.z); o.w = f2bf(v.w);
    *(ushort4*)(dst + off) = o;
}

// ---------------------------------------------------------------------------
// GEMM core (m97-style, XOR-swizzled global_load_lds staging).
// mode 0: bf16 out [B,NH,T,HS]; mode 1: fp32 out [M][N];
// mode 2: bf16 V^T BLOCKED [bh][ktile=64][d=64][kk=32] (contiguous 4KB tiles).
// ---------------------------------------------------------------------------
template <int BN>
__device__ __forceinline__ void gemm_core(const u16* __restrict__ A,
                                          const u16* __restrict__ Bw,
                                          const float* __restrict__ bias,
                                          void* __restrict__ out,
                                          int n0, int mode) {
    __shared__ __align__(16) u16 At[128 * 64];
    __shared__ __align__(16) u16 Bt[BN * 64];
    const int tid = threadIdx.x, w = tid >> 6, lane = tid & 63;
    const int quad = lane >> 4, l16 = lane & 15;
    const int wm = w & 1, wn = w >> 1;
    const int m0 = blockIdx.x * 128;
    constexpr int NTN = BN / 32;
    f32x4 acc[4][NTN] = {};
    const int r8 = lane >> 3, c8 = lane & 7;

    for (int k0 = 0; k0 < Kdim; k0 += 64) {
        __syncthreads();
#pragma unroll
        for (int i = 0; i < 4; ++i) {
            int row = w * 32 + i * 8 + r8;
            int j = c8 ^ (row & 7);
            gl_lds16(A + (size_t)(m0 + row) * Kdim + k0 + j * 8,
                     &At[(w * 32 + i * 8) * 64]);
        }
#pragma unroll
        for (int i = 0; i < BN / 32; ++i) {
            int row = w * (BN / 4) + i * 8 + r8;
            int j = c8 ^ (row & 7);
            gl_lds16(Bw + (size_t)(n0 + row) * Kdim + k0 + j * 8,
                     &Bt[(w * (BN / 4) + i * 8) * 64]);
        }
        __syncthreads();
#pragma unroll
        for (int ks = 0; ks < 2; ++ks) {
            bf16x8 af[4], bf[NTN];
#pragma unroll
            for (int mt = 0; mt < 4; ++mt) {
                int r = wm * 64 + mt * 16 + l16;
                af[mt] = *(const bf16x8*)&At[r * 64 + ((ks * 4 + quad) ^ (r & 7)) * 8];
            }
#pragma unroll
            for (int nt = 0; nt < NTN; ++nt) {
                int r = wn * (BN / 2) + nt * 16 + l16;
                bf[nt] = *(const bf16x8*)&Bt[r * 64 + ((ks * 4 + quad) ^ (r & 7)) * 8];
            }
#pragma unroll
            for (int mt = 0; mt < 4; ++mt)
#pragma unroll
                for (int nt = 0; nt < NTN; ++nt)
                    acc[mt][nt] = __builtin_amdgcn_mfma_f32_16x16x32_bf16(
                        af[mt], bf[nt], acc[mt][nt], 0, 0, 0);
        }
    }

#pragma unroll
    for (int nt = 0; nt < NTN; ++nt) {
        int n = n0 + wn * (BN / 2) + nt * 16 + l16;
        float bb = bias[n];
#pragma unroll
        for (int mt = 0; mt < 4; ++mt) {
            int mbase = m0 + wm * 64 + mt * 16 + quad * 4;
            if (mode == 2) {
                int b = mbase >> 11, t = mbase & 2047;
                int h = n >> 6, d = n & 63;
                int bhid = b * 16 + h;
                int ktb = t >> 5, kkl = t & 31;   // 4 consecutive t = kk
                ushort4 pk;
                pk.x = f2bf(acc[mt][nt][0] + bb);
                pk.y = f2bf(acc[mt][nt][1] + bb);
                pk.z = f2bf(acc[mt][nt][2] + bb);
                pk.w = f2bf(acc[mt][nt][3] + bb);
                *(ushort4*)&((u16*)out)[(size_t)bhid * 131072 + ktb * 2048 + d * 32 + kkl] = pk;
            } else if (mode == 0) {
#pragma unroll
                for (int r = 0; r < 4; ++r) {
                    int m = mbase + r;
                    int b = m >> 11, t = m & 2047, h = n >> 6, d = n & 63;
                    ((u16*)out)[(((size_t)(b * 16 + h) * 2048 + t) << 6) + d] =
                        f2bf(acc[mt][nt][r] + bb);
                }
            } else {
#pragma unroll
                for (int r = 0; r < 4; ++r)
                    ((float*)out)[(size_t)(mbase + r) * Ndim + n] = acc[mt][nt][r] + bb;
            }
        }
    }
}

// fused QKV: grid (32, 24); y<8 -> Q, y<16 -> K, else -> V^T(blocked)
__global__ __launch_bounds__(256, 2) void qkv_gemm(
    const u16* __restrict__ Xb,
    const u16* __restrict__ Wqb, const u16* __restrict__ Wkb, const u16* __restrict__ Wvb,
    const float* __restrict__ bq, const float* __restrict__ bk, const float* __restrict__ bv,
    u16* __restrict__ Qw, u16* __restrict__ Kw, u16* __restrict__ VTw) {
    const int y = blockIdx.y;
    const int z = y >> 3;
    const int n0 = (y & 7) * 128;
    const u16* Bw = (z == 0) ? Wqb : (z == 1) ? Wkb : Wvb;
    const float* bias = (z == 0) ? bq : (z == 1) ? bk : bv;
    void* out = (z == 0) ? (void*)Qw : (z == 1) ? (void*)Kw : (void*)VTw;
    gemm_core<128>(Xb, Bw, bias, out, n0, (z == 2) ? 2 : 0);
}

__global__ __launch_bounds__(256, 2) void out_gemm(
    const u16* __restrict__ Aatt, const u16* __restrict__ Wob,
    const float* __restrict__ bo, float* __restrict__ out) {
    gemm_core<64>(Aatt, Wob, bo, out, blockIdx.y * 64, 1);
}

// ---------------------------------------------------------------------------
// Flash attention v5: transposed-S; 1024 blocks = 32 bh x 32 pairs; every
// block runs strip (63-jj) then strip (jj): 65 tile-units each -> perfectly
// uniform. Within a strip all 4 waves kk-split round-robin; V tiles staged
// via coalesced gl_lds16 from BLOCKED V^T (4KB contiguous/tile) into private
// per-wave LDS double-buffers; K fragments register-direct (contiguous 4KB
// tiles). No barriers in the loop; vmcnt(8) ping-pong. Partials combined in
// LDS (aliased with V staging) per strip.
// ---------------------------------------------------------------------------
__global__ __launch_bounds__(256, 4) void flash_attn(
    const u16* __restrict__ Q, const u16* __restrict__ K,
    const u16* __restrict__ VT, u16* __restrict__ Aatt) {
    __shared__ __align__(16) u16 SBuf[16384];       // 32KB: V staging / O-combine alias
    __shared__ float lsumLds[4][32];

    const int tid = threadIdx.x, w = tid >> 6, lane = tid & 63;
    const int quad = lane >> 4, l16 = lane & 15;
    const int g = blockIdx.x;
    const int bh = g & 31;
    const int jj = g >> 5;                  // 0..31

    const u16* Qh  = Q  + (size_t)bh * 131072;
    const u16* Kh  = K  + (size_t)bh * 131072;
    const u16* VTh = VT + (size_t)bh * 131072;
    const int b = bh >> 4, h = bh & 15;
    const float c1 = 0.18033688011112042f;  // log2(e)/8

#define VSTAGE(buf_, kt_)                                                      \
    {                                                                          \
        const u16* src_ = VTh + (size_t)(kt_) * 2048;                          \
        u16* dst_ = &SBuf[((w << 1) + (buf_)) * 2048];                         \
        _Pragma("unroll")                                                      \
        for (int i_ = 0; i_ < 4; ++i_)                                         \
            gl_lds16(src_ + i_ * 512 + lane * 8, dst_ + i_ * 512);             \
    }

#define KLOAD(kt_, ka_)                                                        \
    {                                                                          \
        const u16* kp_ = Kh + (size_t)(kt_) * 2048;                            \
        _Pragma("unroll")                                                      \
        for (int c_ = 0; c_ < 2; ++c_)                                         \
            _Pragma("unroll")                                                  \
            for (int ks_ = 0; ks_ < 2; ++ks_)                                  \
                ka_[c_][ks_] = *(const bf16x8*)(kp_ + (c_ * 16 + l16) * 64     \
                                                + ks_ * 32 + quad * 8);        \
    }

#define COMPUTE(kt_, ka_, buf_)                                                \
    {                                                                          \
        const u16* vb_ = &SBuf[((w << 1) + (buf_)) * 2048];                    \
        const bool dm_ = ((kt_) == ntw - 1);                                   \
        _Pragma("unroll")                                                      \
        for (int c_ = 0; c_ < 2; ++c_) {                                       \
            s16x4 vf_[4];                                                      \
            _Pragma("unroll")                                                  \
            for (int dt_ = 0; dt_ < 4; ++dt_)                                  \
                vf_[dt_] = *(const s16x4*)&vb_[(dt_ * 16 + l16) * 32           \
                                               + c_ * 16 + quad * 4];          \
            _Pragma("unroll")                                                  \
            for (int qt_ = 0; qt_ < 2; ++qt_) {                                \
                f32x4 z_ = {};                                                 \
                z_ = __builtin_amdgcn_mfma_f32_16x16x32_bf16(                  \
                    ka_[c_][0], qf[qt_][0], z_, 0, 0, 0);                      \
                z_ = __builtin_amdgcn_mfma_f32_16x16x32_bf16(                  \
                    ka_[c_][1], qf[qt_][1], z_, 0, 0, 0);                      \
                float p_[4];                                                   \
                if (dm_) {                                                     \
                    int q_ = qbase + qt_ * 16 + l16;                           \
                    int kkb_ = (kt_) * 32 + c_ * 16 + quad * 4;                \
                    _Pragma("unroll")                                          \
                    for (int r_ = 0; r_ < 4; ++r_)                             \
                        p_[r_] = (kkb_ + r_ > q_) ? 0.f : EXP2(z_[r_] * c1);   \
                } else {                                                       \
                    _Pragma("unroll")                                          \
                    for (int r_ = 0; r_ < 4; ++r_) p_[r_] = EXP2(z_[r_] * c1); \
                }                                                              \
                lsum[qt_] += (p_[0] + p_[1]) + (p_[2] + p_[3]);                \
                s16x4 pa_ = pack4bf(p_[0], p_[1], p_[2], p_[3]);               \
                _Pragma("unroll")                                              \
                for (int dt_ = 0; dt_ < 4; ++dt_)                              \
                    o[qt_][dt_] = mfma16(pa_, vf_[dt_], o[qt_][dt_]);          \
            }                                                                  \
        }                                                                      \
    }

#pragma unroll 1
    for (int phase = 0; phase < 2; ++phase) {
        const int strip = phase ? jj : (63 - jj);
        const int qbase = strip * 32;
        const int ntw = strip + 1;

        // Q fragments (B operand)
        bf16x8 qf[2][2];
#pragma unroll
        for (int qt = 0; qt < 2; ++qt)
#pragma unroll
            for (int ks = 0; ks < 2; ++ks)
                qf[qt][ks] = *(const bf16x8*)(Qh + (size_t)(qbase + qt * 16 + l16) * 64
                                                 + ks * 32 + quad * 8);

        f32x4 o[2][4] = {};
        float lsum[2] = {0.f, 0.f};

        bf16x8 kaA[2][2], kaB[2][2];
        int kt = w;                        // round-robin kk-split across waves
        if (kt < ntw) {
            VSTAGE(0, kt);
            KLOAD(kt, kaA);
            while (true) {
                int nx = kt + 4;
                if (nx < ntw) {
                    VSTAGE(1, nx); KLOAD(nx, kaB);
                    asm volatile("s_waitcnt vmcnt(8)" ::: "memory");
                } else {
                    asm volatile("s_waitcnt vmcnt(0)" ::: "memory");
                }
                COMPUTE(kt, kaA, 0);
                kt = nx;
                if (kt >= ntw) break;
                nx = kt + 4;
                if (nx < ntw) {
                    VSTAGE(0, nx); KLOAD(nx, kaA);
                    asm volatile("s_waitcnt vmcnt(8)" ::: "memory");
                } else {
                    asm volatile("s_waitcnt vmcnt(0)" ::: "memory");
                }
                COMPUTE(kt, kaB, 1);
                kt = nx;
                if (kt >= ntw) break;
            }
        }

        // ---- combine 4 waves' partials (plain sums: no running max) ----
        __syncthreads();                    // all waves done using SBuf as V
        float* oPart = (float*)SBuf;        // [wave][32 q][64 d]
#pragma unroll
        for (int qt = 0; qt < 2; ++qt) {
            float l = lsum[qt];
            l += __shfl_xor(l, 16);
            l += __shfl_xor(l, 32);
            if (lane < 16) lsumLds[w][qt * 16 + lane] = l;
#pragma unroll
            for (int dt = 0; dt < 4; ++dt)
#pragma unroll
                for (int r = 0; r < 4; ++r)
                    oPart[w * 2048 + (qt * 16 + quad * 4 + r) * 64 + dt * 16 + l16] =
                        o[qt][dt][r];
        }
        __syncthreads();
        {
            const int q = tid >> 3, d = (tid & 7) * 8;
            float l = lsumLds[0][q] + lsumLds[1][q] + lsumLds[2][q] + lsumLds[3][q];
            float inv = 1.0f / l;
            f32x4 a0 = {}, a1 = {};
#pragma unroll
            for (int ww = 0; ww < 4; ++ww) {
                a0 += *(const f32x4*)&oPart[ww * 2048 + q * 64 + d];
                a1 += *(const f32x4*)&oPart[ww * 2048 + q * 64 + d + 4];
            }
            const int t = qbase + q;
            ushort4 p0, p1;
            p0.x = f2bf(a0[0] * inv); p0.y = f2bf(a0[1] * inv);
            p0.z = f2bf(a0[2] * inv); p0.w = f2bf(a0[3] * inv);
            p1.x = f2bf(a1[0] * inv); p1.y = f2bf(a1[1] * inv);
            p1.z = f2bf(a1[2] * inv); p1.w = f2bf(a1[3] * inv);
            u16* dst = Aatt + ((size_t)(b * 2048 + t)) * 1024 + h * 64 + d;
            *(ushort4*)dst = p0;
            *(ushort4*)(dst + 4) = p1;
        }
        __syncthreads();                    // oPart reads done before next VSTAGE
    }
}

// ---------------------------------------------------------------------------
extern "C" void kernel_launch(void* const* d_in, const int* in_sizes, int n_in,
                              void* d_out, int out_size, void* d_ws, size_t ws_size,
                              hipStream_t stream) {
    const float* X  = (const float*)d_in[0];
    const float* Wq = (const float*)d_in[1];
    const float* bq = (const float*)d_in[2];
    const float* Wk = (const float*)d_in[3];
    const float* bk = (const float*)d_in[4];
    const float* Wv = (const float*)d_in[5];
    const float* bv = (const float*)d_in[6];
    const float* Wo = (const float*)d_in[7];
    const float* bo = (const float*)d_in[8];

    char* ws = (char*)d_ws;
    const size_t MB = 1 << 20;
    u16* Xb   = (u16*)(ws);
    u16* Wqb  = (u16*)(ws + 8  * MB);
    u16* Wkb  = (u16*)(ws + 10 * MB);
    u16* Wvb  = (u16*)(ws + 12 * MB);
    u16* Wob  = (u16*)(ws + 14 * MB);
    u16* Qw   = (u16*)(ws + 16 * MB);   // [bh][t][d]
    u16* Kw   = (u16*)(ws + 24 * MB);   // [bh][t][d]
    u16* VTw  = (u16*)(ws + 32 * MB);   // [bh][ktile][d][kk] blocked
    u16* Aatt = (u16*)(ws + 40 * MB);   // [B][T][E]

    cast_all<<<8192, 256, 0, stream>>>(X, Wq, Wk, Wv, Wo, Xb, Wqb, Wkb, Wvb, Wob);
    qkv_gemm<<<dim3(32, 24), 256, 0, stream>>>(Xb, Wqb, Wkb, Wvb, bq, bk, bv, Qw, Kw, VTw);
    flash_attn<<<dim3(1024), 256, 0, stream>>>(Qw, Kw, VTw, Aatt);
    out_gemm<<<dim3(32, 16), 256, 0, stream>>>(Aatt, Wob, bo, (float*)d_out);
}

// Round 6
// 167.447 us; speedup vs baseline: 1.3688x; 1.1485x over previous
//
#include <hip/hip_runtime.h>

typedef unsigned short u16;
typedef __bf16 bf16x8 __attribute__((ext_vector_type(8)));
typedef __bf16 bf16x4 __attribute__((ext_vector_type(4)));
typedef __bf16 bf16x2 __attribute__((ext_vector_type(2)));
typedef short s16x4 __attribute__((ext_vector_type(4)));
typedef float f32x4 __attribute__((ext_vector_type(4)));

#define Mdim 4096
#define Ndim 1024
#define Kdim 1024

__device__ __forceinline__ u16 f2bf(float f) {
    unsigned u = __float_as_uint(f);
    u += 0x7FFF + ((u >> 16) & 1);   // RNE
    return (u16)(u >> 16);
}

// async global->LDS, 16B/lane; LDS dst = wave-uniform base + lane*16
__device__ __forceinline__ void gl_lds16(const u16* g, u16* l) {
    __builtin_amdgcn_global_load_lds(
        (const __attribute__((address_space(1))) unsigned int*)g,
        (__attribute__((address_space(3))) unsigned int*)l, 16, 0, 0);
}

__device__ __forceinline__ f32x4 mfma16(s16x4 a, s16x4 b, f32x4 c) {
#if __has_builtin(__builtin_amdgcn_mfma_f32_16x16x16_bf16)
    return __builtin_amdgcn_mfma_f32_16x16x16_bf16(
        __builtin_bit_cast(bf16x4, a), __builtin_bit_cast(bf16x4, b), c, 0, 0, 0);
#else
    return __builtin_amdgcn_mfma_f32_16x16x16bf16_1k(a, b, c, 0, 0, 0);
#endif
}

#if __has_builtin(__builtin_amdgcn_exp2f)
#define EXP2(x) __builtin_amdgcn_exp2f(x)
#else
#define EXP2(x) exp2f(x)
#endif

__device__ __forceinline__ s16x4 pack4bf(float a, float b, float c, float d) {
#if __has_builtin(__builtin_amdgcn_cvt_pk_bf16_f32)
    union { struct { bf16x2 lo, hi; } v; s16x4 s; } u;
    u.v.lo = __builtin_amdgcn_cvt_pk_bf16_f32(a, b);
    u.v.hi = __builtin_amdgcn_cvt_pk_bf16_f32(c, d);
    return u.s;
#else
    s16x4 r;
    r.x = (short)f2bf(a); r.y = (short)f2bf(b);
    r.z = (short)f2bf(c); r.w = (short)f2bf(d);
    return r;
#endif
}

// ---------------------------------------------------------------------------
// Kernel 1: cast X and Wq/Wk/Wv/Wo fp32 -> bf16
// ---------------------------------------------------------------------------
__global__ __launch_bounds__(256) void cast_all(
    const float* __restrict__ X,
    const float* __restrict__ Wq, const float* __restrict__ Wk,
    const float* __restrict__ Wv, const float* __restrict__ Wo,
    u16* __restrict__ Xb,
    u16* __restrict__ Wqb, u16* __restrict__ Wkb,
    u16* __restrict__ Wvb, u16* __restrict__ Wob) {
    size_t i4 = (size_t)blockIdx.x * blockDim.x + threadIdx.x;
    size_t flat = i4 * 4;
    const float* src;
    u16* dst;
    size_t off;
    if (flat < (size_t)4194304) {
        src = X; dst = Xb; off = flat;
    } else {
        size_t r = flat - 4194304;
        int w = (int)(r >> 20);
        off = r & 1048575;
        src = (w == 0) ? Wq : (w == 1) ? Wk : (w == 2) ? Wv : Wo;
        dst = (w == 0) ? Wqb : (w == 1) ? Wkb : (w == 2) ? Wvb : Wob;
    }
    float4 v = *(const float4*)(src + off);
    ushort4 o;
    o.x = f2bf(v.x); o.y = f2bf(v.y); o.z = f2bf(v.z); o.w = f2bf(v.w);
    *(ushort4*)(dst + off) = o;
}

// ---------------------------------------------------------------------------
// GEMM core (m97-style, XOR-swizzled global_load_lds staging).
// mode 1: fp32 out [M][N]
// mode 2: V in PV-B-fragment order:  [bh][kt][c*4+dt][lane][4]   (8B stores)
// mode 3: Q in QK-B-fragment order:  [bh][strip][qt*2+ks][lane][8] (2B stores)
// mode 4: K in QK-A-fragment order:  [bh][kt][c*2+ks][lane][8]   (2B stores)
// Fragment conventions (16x16 MFMA, lane = quadf*16 + l16f):
//   A-op x32: lane holds A[m=l16f][k=quadf*8+jj]      (16B)
//   B-op x32: lane holds B[k=quadf*8+jj][n=l16f]      (16B)
//   B-op x16: lane holds B[k=quadf*4+j][n=l16f]       (8B)
// ---------------------------------------------------------------------------
template <int BN>
__device__ __forceinline__ void gemm_core(const u16* __restrict__ A,
                                          const u16* __restrict__ Bw,
                                          const float* __restrict__ bias,
                                          void* __restrict__ out,
                                          int n0, int mode) {
    __shared__ __align__(16) u16 At[128 * 64];
    __shared__ __align__(16) u16 Bt[BN * 64];
    const int tid = threadIdx.x, w = tid >> 6, lane = tid & 63;
    const int quad = lane >> 4, l16 = lane & 15;
    const int wm = w & 1, wn = w >> 1;
    const int m0 = blockIdx.x * 128;
    constexpr int NTN = BN / 32;
    f32x4 acc[4][NTN] = {};
    const int r8 = lane >> 3, c8 = lane & 7;

    for (int k0 = 0; k0 < Kdim; k0 += 64) {
        __syncthreads();
#pragma unroll
        for (int i = 0; i < 4; ++i) {
            int row = w * 32 + i * 8 + r8;
            int j = c8 ^ (row & 7);
            gl_lds16(A + (size_t)(m0 + row) * Kdim + k0 + j * 8,
                     &At[(w * 32 + i * 8) * 64]);
        }
#pragma unroll
        for (int i = 0; i < BN / 32; ++i) {
            int row = w * (BN / 4) + i * 8 + r8;
            int j = c8 ^ (row & 7);
            gl_lds16(Bw + (size_t)(n0 + row) * Kdim + k0 + j * 8,
                     &Bt[(w * (BN / 4) + i * 8) * 64]);
        }
        __syncthreads();
#pragma unroll
        for (int ks = 0; ks < 2; ++ks) {
            bf16x8 af[4], bf[NTN];
#pragma unroll
            for (int mt = 0; mt < 4; ++mt) {
                int r = wm * 64 + mt * 16 + l16;
                af[mt] = *(const bf16x8*)&At[r * 64 + ((ks * 4 + quad) ^ (r & 7)) * 8];
            }
#pragma unroll
            for (int nt = 0; nt < NTN; ++nt) {
                int r = wn * (BN / 2) + nt * 16 + l16;
                bf[nt] = *(const bf16x8*)&Bt[r * 64 + ((ks * 4 + quad) ^ (r & 7)) * 8];
            }
#pragma unroll
            for (int mt = 0; mt < 4; ++mt)
#pragma unroll
                for (int nt = 0; nt < NTN; ++nt)
                    acc[mt][nt] = __builtin_amdgcn_mfma_f32_16x16x32_bf16(
                        af[mt], bf[nt], acc[mt][nt], 0, 0, 0);
        }
    }

#pragma unroll
    for (int nt = 0; nt < NTN; ++nt) {
        int n = n0 + wn * (BN / 2) + nt * 16 + l16;
        float bb = bias[n];
        // n-derived fragment coords (modes 2/3/4)
        const int h = n >> 6, d = n & 63;
        const int ksf = (d >> 5) & 1, quadf8 = (d >> 3) & 3, jj = d & 7;
        const int dtf = d >> 4, l16f = d & 15;
#pragma unroll
        for (int mt = 0; mt < 4; ++mt) {
            int mbase = m0 + wm * 64 + mt * 16 + quad * 4;
            if (mode == 2) {
                // V fragment: kk=t within tile: c=kl>>4, quadf=(kl>>2)&3, j=r
                int b = mbase >> 11, t = mbase & 2047;
                int kt = t >> 5, kl = t & 31;
                int c = kl >> 4, quadf = (kl >> 2) & 3;
                ushort4 pk;
                pk.x = f2bf(acc[mt][nt][0] + bb);
                pk.y = f2bf(acc[mt][nt][1] + bb);
                pk.z = f2bf(acc[mt][nt][2] + bb);
                pk.w = f2bf(acc[mt][nt][3] + bb);
                *(ushort4*)&((u16*)out)[(size_t)(b * 16 + h) * 131072 + kt * 2048 +
                                        (c * 4 + dtf) * 256 + (quadf * 16 + l16f) * 4] = pk;
            } else if (mode == 3 || mode == 4) {
#pragma unroll
                for (int r = 0; r < 4; ++r) {
                    int m = mbase + r;
                    int b = m >> 11, t = m & 2047;
                    int blk = t >> 5, tl = t & 31;
                    int cq = tl >> 4, l16q = tl & 15;   // qt or c ; q/kk row
                    ((u16*)out)[(size_t)(b * 16 + h) * 131072 + blk * 2048 +
                                (cq * 2 + ksf) * 512 + (quadf8 * 16 + l16q) * 8 + jj] =
                        f2bf(acc[mt][nt][r] + bb);
                }
            } else {
#pragma unroll
                for (int r = 0; r < 4; ++r)
                    ((float*)out)[(size_t)(mbase + r) * Ndim + n] = acc[mt][nt][r] + bb;
            }
        }
    }
}

// fused QKV: grid (32, 24); y<8 -> Q(frag), y<16 -> K(frag), else -> V(frag)
__global__ __launch_bounds__(256, 2) void qkv_gemm(
    const u16* __restrict__ Xb,
    const u16* __restrict__ Wqb, const u16* __restrict__ Wkb, const u16* __restrict__ Wvb,
    const float* __restrict__ bq, const float* __restrict__ bk, const float* __restrict__ bv,
    u16* __restrict__ Qw, u16* __restrict__ Kw, u16* __restrict__ Vw) {
    const int y = blockIdx.y;
    const int z = y >> 3;
    const int n0 = (y & 7) * 128;
    const u16* Bw = (z == 0) ? Wqb : (z == 1) ? Wkb : Wvb;
    const float* bias = (z == 0) ? bq : (z == 1) ? bk : bv;
    void* out = (z == 0) ? (void*)Qw : (z == 1) ? (void*)Kw : (void*)Vw;
    gemm_core<128>(Xb, Bw, bias, out, n0, (z == 0) ? 3 : (z == 1) ? 4 : 2);
}

__global__ __launch_bounds__(256, 2) void out_gemm(
    const u16* __restrict__ Aatt, const u16* __restrict__ Wob,
    const float* __restrict__ bo, float* __restrict__ out) {
    gemm_core<64>(Aatt, Wob, bo, out, blockIdx.y * 64, 1);
}

// ---------------------------------------------------------------------------
// Flash attention v6: transposed-S; Q/K/V pre-swizzled into MFMA-fragment
// order so ALL loads are register-direct and perfectly lane-linear
// (K: dwordx4 @ base+lane*16, V: dwordx2 @ base+lane*8). Zero LDS / zero
// bank conflicts / zero lgkmcnt in the loop; register ping-pong with
// vmcnt(12). 2048 one-strip blocks, heavy-first; 4 waves kk-split per strip;
// partials combined once in padded LDS.
// ---------------------------------------------------------------------------
__global__ __launch_bounds__(256, 3) void flash_attn(
    const u16* __restrict__ QF, const u16* __restrict__ KF,
    const u16* __restrict__ VF, u16* __restrict__ Aatt) {
    __shared__ float oLds[4 * 2112];          // [wave][32 q][stride 66]
    __shared__ float lsumLds[4][32];

    const int tid = threadIdx.x, w = tid >> 6, lane = tid & 63;
    const int quad = lane >> 4, l16 = lane & 15;
    const int g = blockIdx.x;
    const int bh = g & 31;
    const int strip = 63 - (g >> 5);          // heavy first
    const int qbase = strip * 32;
    const int ntw = strip + 1;

    const u16* QFh = QF + (size_t)bh * 131072;
    const u16* KFh = KF + (size_t)bh * 131072;
    const u16* VFh = VF + (size_t)bh * 131072;
    const int b = bh >> 4, h = bh & 15;
    const float c1 = 0.18033688011112042f;    // log2(e)/8

    // Q fragments: dense 16B/lane
    bf16x8 qf[2][2];
#pragma unroll
    for (int qt = 0; qt < 2; ++qt)
#pragma unroll
        for (int ks = 0; ks < 2; ++ks)
            qf[qt][ks] = *(const bf16x8*)(QFh + (size_t)strip * 2048 +
                                          (qt * 2 + ks) * 512 + lane * 8);

    f32x4 o[2][4] = {};
    float lsum[2] = {0.f, 0.f};

#define LOADT(kt_, ka_, vf_)                                                   \
    {                                                                          \
        const u16* kp_ = KFh + (size_t)(kt_) * 2048;                           \
        const u16* vp_ = VFh + (size_t)(kt_) * 2048;                           \
        _Pragma("unroll")                                                      \
        for (int c_ = 0; c_ < 2; ++c_) {                                       \
            _Pragma("unroll")                                                  \
            for (int ks_ = 0; ks_ < 2; ++ks_)                                  \
                ka_[c_][ks_] = *(const bf16x8*)(kp_ + (c_ * 2 + ks_) * 512     \
                                                + lane * 8);                   \
            _Pragma("unroll")                                                  \
            for (int dt_ = 0; dt_ < 4; ++dt_)                                  \
                vf_[c_][dt_] = *(const s16x4*)(vp_ + (c_ * 4 + dt_) * 256      \
                                               + lane * 4);                    \
        }                                                                      \
    }

#define COMPUTE(kt_, ka_, vf_)                                                 \
    {                                                                          \
        const bool dm_ = ((kt_) == ntw - 1);                                   \
        _Pragma("unroll")                                                      \
        for (int c_ = 0; c_ < 2; ++c_) {                                       \
            _Pragma("unroll")                                                  \
            for (int qt_ = 0; qt_ < 2; ++qt_) {                                \
                f32x4 z_ = {};                                                 \
                z_ = __builtin_amdgcn_mfma_f32_16x16x32_bf16(                  \
                    ka_[c_][0], qf[qt_][0], z_, 0, 0, 0);                      \
                z_ = __builtin_amdgcn_mfma_f32_16x16x32_bf16(                  \
                    ka_[c_][1], qf[qt_][1], z_, 0, 0, 0);                      \
                float p_[4];                                                   \
                if (dm_) {                                                     \
                    int q_ = qbase + qt_ * 16 + l16;                           \
                    int kkb_ = (kt_) * 32 + c_ * 16 + quad * 4;                \
                    _Pragma("unroll")                                          \
                    for (int r_ = 0; r_ < 4; ++r_)                             \
                        p_[r_] = (kkb_ + r_ > q_) ? 0.f : EXP2(z_[r_] * c1);   \
                } else {                                                       \
                    _Pragma("unroll")                                          \
                    for (int r_ = 0; r_ < 4; ++r_) p_[r_] = EXP2(z_[r_] * c1); \
                }                                                              \
                lsum[qt_] += (p_[0] + p_[1]) + (p_[2] + p_[3]);                \
                s16x4 pa_ = pack4bf(p_[0], p_[1], p_[2], p_[3]);               \
                _Pragma("unroll")                                              \
                for (int dt_ = 0; dt_ < 4; ++dt_)                              \
                    o[qt_][dt_] = mfma16(pa_, vf_[c_][dt_], o[qt_][dt_]);      \
            }                                                                  \
        }                                                                      \
    }

    bf16x8 kaA[2][2], kaB[2][2];
    s16x4 vfA[2][4], vfB[2][4];
    int kt = w;                                // round-robin kk-split
    if (kt < ntw) {
        LOADT(kt, kaA, vfA);
        while (true) {
            int nx = kt + 4;
            if (nx < ntw) {
                LOADT(nx, kaB, vfB);
                asm volatile("s_waitcnt vmcnt(12)" ::: "memory");
            } else {
                asm volatile("s_waitcnt vmcnt(0)" ::: "memory");
            }
            COMPUTE(kt, kaA, vfA);
            kt = nx;
            if (kt >= ntw) break;
            nx = kt + 4;
            if (nx < ntw) {
                LOADT(nx, kaA, vfA);
                asm volatile("s_waitcnt vmcnt(12)" ::: "memory");
            } else {
                asm volatile("s_waitcnt vmcnt(0)" ::: "memory");
            }
            COMPUTE(kt, kaB, vfB);
            kt = nx;
            if (kt >= ntw) break;
        }
    }

    // ---- combine 4 waves' partials (plain sums: no running max) ----
#pragma unroll
    for (int qt = 0; qt < 2; ++qt) {
        float l = lsum[qt];
        l += __shfl_xor(l, 16);
        l += __shfl_xor(l, 32);
        if (lane < 16) lsumLds[w][qt * 16 + lane] = l;
#pragma unroll
        for (int dt = 0; dt < 4; ++dt)
#pragma unroll
            for (int r = 0; r < 4; ++r)
                oLds[w * 2112 + (qt * 16 + quad * 4 + r) * 66 + dt * 16 + l16] =
                    o[qt][dt][r];
    }
    __syncthreads();
    {
        const int q = tid >> 3, dd = (tid & 7) * 8;
        float l = lsumLds[0][q] + lsumLds[1][q] + lsumLds[2][q] + lsumLds[3][q];
        float inv = 1.0f / l;
        f32x4 a0 = {}, a1 = {};
#pragma unroll
        for (int ww = 0; ww < 4; ++ww) {
            a0 += *(const f32x4*)&oLds[ww * 2112 + q * 66 + dd];
            a1 += *(const f32x4*)&oLds[ww * 2112 + q * 66 + dd + 4];
        }
        const int t = qbase + q;
        ushort4 p0, p1;
        p0.x = f2bf(a0[0] * inv); p0.y = f2bf(a0[1] * inv);
        p0.z = f2bf(a0[2] * inv); p0.w = f2bf(a0[3] * inv);
        p1.x = f2bf(a1[0] * inv); p1.y = f2bf(a1[1] * inv);
        p1.z = f2bf(a1[2] * inv); p1.w = f2bf(a1[3] * inv);
        u16* dst = Aatt + ((size_t)(b * 2048 + t)) * 1024 + h * 64 + dd;
        *(ushort4*)dst = p0;
        *(ushort4*)(dst + 4) = p1;
    }
}

// ---------------------------------------------------------------------------
extern "C" void kernel_launch(void* const* d_in, const int* in_sizes, int n_in,
                              void* d_out, int out_size, void* d_ws, size_t ws_size,
                              hipStream_t stream) {
    const float* X  = (const float*)d_in[0];
    const float* Wq = (const float*)d_in[1];
    const float* bq = (const float*)d_in[2];
    const float* Wk = (const float*)d_in[3];
    const float* bk = (const float*)d_in[4];
    const float* Wv = (const float*)d_in[5];
    const float* bv = (const float*)d_in[6];
    const float* Wo = (const float*)d_in[7];
    const float* bo = (const float*)d_in[8];

    char* ws = (char*)d_ws;
    const size_t MB = 1 << 20;
    u16* Xb   = (u16*)(ws);
    u16* Wqb  = (u16*)(ws + 8  * MB);
    u16* Wkb  = (u16*)(ws + 10 * MB);
    u16* Wvb  = (u16*)(ws + 12 * MB);
    u16* Wob  = (u16*)(ws + 14 * MB);
    u16* Qw   = (u16*)(ws + 16 * MB);   // [bh][strip][frag] (B-op order)
    u16* Kw   = (u16*)(ws + 24 * MB);   // [bh][kt][frag]    (A-op order)
    u16* Vw   = (u16*)(ws + 32 * MB);   // [bh][kt][frag]    (B-op x16 order)
    u16* Aatt = (u16*)(ws + 40 * MB);   // [B][T][E]

    cast_all<<<8192, 256, 0, stream>>>(X, Wq, Wk, Wv, Wo, Xb, Wqb, Wkb, Wvb, Wob);
    qkv_gemm<<<dim3(32, 24), 256, 0, stream>>>(Xb, Wqb, Wkb, Wvb, bq, bk, bv, Qw, Kw, Vw);
    flash_attn<<<dim3(2048), 256, 0, stream>>>(Qw, Kw, Vw, Aatt);
    out_gemm<<<dim3(32, 16), 256, 0, stream>>>(Aatt, Wob, bo, (float*)d_out);
}